// Round 13
// baseline (183.350 us; speedup 1.0000x reference)
//
#include <hip/hip_runtime.h>
#include <math.h>

#define N_BOX 8192
#define NW 128              // 8192 / 64 words
#define LCAP 24576          // edges staged in LDS (96 KiB)
#define ECAP_MAX (1 << 21)  // max edges in global buffer (8 MiB)
#define PBLK 128            // persistent blocks for pair phase
#define THR_C 0.7f
#define IOU_THR_C 0.5f
#define EPS_C 1e-9f

// SCALER = max(3508/1280, 2480/1280) computed in double then rounded to f32,
// matching numpy/jax float32 weak-typed scalar promotion.
__device__ __constant__ float kScaler = (float)(3508.0 / 1280.0);

static __device__ __forceinline__ unsigned long long make_key(const float* conf, int i) {
    float c0 = conf[2 * i], c1 = conf[2 * i + 1];
    bool valid = (c0 > THR_C) || (c1 > THR_C);
    float ms = valid ? fmaxf(c0, c1) : -INFINITY;
    unsigned int u = __float_as_uint(ms);
    unsigned int m = (u & 0x80000000u) ? ~u : (u | 0x80000000u); // ascending map
    unsigned int d = ~m;                                          // descending key
    return ((unsigned long long)d << 32) | (unsigned int)i;
}

// ---------------------------------------------------------------------------
// K1: 4 blocks sort 2048-chunks (verified network, global-index directions),
// then the LAST block to finish (spin-free: fence + atomicAdd(done) returns
// gridDim-1 only after every other block's fenced writes) runs the full
// k=4096 + k=8192 merge on all 8192 keys in LDS and gathers sb/order/validw
// and nv (valid boxes occupy ranks [0,nv); invalid sort last with -inf keys).
// ---------------------------------------------------------------------------
__global__ __launch_bounds__(1024) void sort_kernel(const float* __restrict__ conf,
                                                    const float* __restrict__ bboxes,
                                                    unsigned long long* __restrict__ keys,
                                                    float4* __restrict__ sb,
                                                    unsigned int* __restrict__ order,
                                                    unsigned long long* __restrict__ validw,
                                                    int* __restrict__ nvD,
                                                    int* __restrict__ done1) {
    __shared__ unsigned long long s[N_BOX];   // 64 KiB (chunk phase uses 2048)
    __shared__ int isLastS;
    int bid = blockIdx.x;
    int t = threadIdx.x;
    int base = bid * 2048;
    // --- chunk sort (k<=2048, directions from GLOBAL index) ---
    for (int l = t; l < 2048; l += 1024) s[l] = make_key(conf, base + l);
    __syncthreads();
    for (int k = 2; k <= 2048; k <<= 1) {
        for (int j = k >> 1; j > 0; j >>= 1) {
            int i = ((t & ~(j - 1)) << 1) | (t & (j - 1));
            int p = i | j;
            bool up = (((base + i) & k) == 0);
            unsigned long long a = s[i], b = s[p];
            bool sw = up ? (a > b) : (a < b);
            if (sw) { s[i] = b; s[p] = a; }
            __syncthreads();
        }
    }
    for (int l = t; l < 2048; l += 1024) keys[base + l] = s[l];
    __syncthreads();
    if (t == 0) {
        __threadfence();                       // publish chunk keys
        isLastS = (atomicAdd(done1, 1) == 3);  // spin-free last-block election
    }
    __syncthreads();
    if (!isLastS) return;
    __threadfence();                           // acquire other chunks
    // --- full merge: k=4096 (j=2048..1), then k=8192 (j=4096..1, ascending) ---
    for (int l = t; l < N_BOX; l += 1024) s[l] = keys[l];
    __syncthreads();
    for (int j = 2048; j > 0; j >>= 1) {
        for (int t2 = t; t2 < 4096; t2 += 1024) {
            int i = ((t2 & ~(j - 1)) << 1) | (t2 & (j - 1));
            int p = i | j;
            bool up = ((i & 4096) == 0);
            unsigned long long a = s[i], b = s[p];
            bool sw = up ? (a > b) : (a < b);
            if (sw) { s[i] = b; s[p] = a; }
        }
        __syncthreads();
    }
    for (int j = 4096; j > 0; j >>= 1) {       // k=8192: all ascending
        for (int t2 = t; t2 < 4096; t2 += 1024) {
            int i = ((t2 & ~(j - 1)) << 1) | (t2 & (j - 1));
            int p = i | j;
            unsigned long long a = s[i], b = s[p];
            if (a > b) { s[i] = b; s[p] = a; }
        }
        __syncthreads();
    }
    // --- gather ---
    for (int l = t; l < N_BOX; l += 1024) {
        unsigned int o = (unsigned int)(s[l] & 0xffffffffull);
        order[l] = o;
        sb[l] = ((const float4*)bboxes)[o];
        float c0 = conf[2 * o], c1 = conf[2 * o + 1];
        unsigned long long vb = __ballot((c0 > THR_C) || (c1 > THR_C));
        if ((l & 63) == 0) {
            validw[l >> 6] = vb;
            atomicAdd(nvD, __popcll(vb));
        }
    }
}

// LDS overlay for K2: pair tile vs Jacobi state (phases block-disjoint in time).
union SMem2 {
    struct { float4 cb[64]; float carea[64]; } p;
    struct {
        unsigned int eL[LCAP];                 // 96 KiB
        unsigned long long kL[NW], tL[NW], vL[NW];
        int chg[3];
    } j;
};

// ---------------------------------------------------------------------------
// K2: persistent-block pair phase (verified edge-list code: nv x nv upper
// triangle, edge=(src<<13)|tgt, both valid, wave-aggregated append), then the
// LAST block (spin-free election, as K1) runs the verified Jacobi fixpoint
// (greedy NMS = unique fixpoint of k=v&~OR kept-predecessors; k_new==k_old
// certifies convergence) and writes the fused (N,6) output. Overflow
// (cnt > ecap, never expected at ~10K edges) -> serial on-the-fly greedy.
// ---------------------------------------------------------------------------
__global__ __launch_bounds__(1024) void pair_scan_kernel(const float4* __restrict__ sb,
                                                         const unsigned int* __restrict__ order,
                                                         const float* __restrict__ conf,
                                                         const unsigned long long* __restrict__ validw,
                                                         const int* __restrict__ nvD,
                                                         unsigned int* __restrict__ edges,
                                                         int* __restrict__ ecntE,
                                                         int* __restrict__ done2,
                                                         float* __restrict__ out,
                                                         int ecap) {
    __shared__ SMem2 sm;
    __shared__ int isLastS;
    int t = threadIdx.x;
    int lane = t & 63;
    int nv = *nvD;
    // --- pair tiles: 8 i-tiles (1024 rows) x 128 j-words, grid-stride ---
    for (int tile = blockIdx.x; tile < 8 * 128; tile += PBLK) {
        int iblk = tile & 7;
        int w = tile >> 3;
        int ibase = iblk << 10, jbase = w << 6;
        if (ibase >= nv || jbase >= nv || jbase + 63 <= ibase) continue; // uniform
        if (t < 64) {
            float4 c = sb[jbase + t];
            sm.p.cb[t] = c;
            sm.p.carea[t] = (c.z - c.x) * (c.w - c.y);
        }
        __syncthreads();
        int i = ibase + t;
        unsigned long long bits = 0ull;
        if (i < nv && jbase + 63 > i) {
            float4 r = sb[i];
            float ra = (r.z - r.x) * (r.w - r.y);
#pragma unroll 8
            for (int b = 0; b < 64; ++b) {
                float4 c = sm.p.cb[b];
                float iw = fminf(r.z, c.z) - fmaxf(r.x, c.x);
                float ih = fminf(r.w, c.w) - fmaxf(r.y, c.y);
                iw = fmaxf(iw, 0.0f);
                ih = fmaxf(ih, 0.0f);
                float inter = iw * ih;
                float iou = inter / (ra + sm.p.carea[b] - inter + EPS_C);
                if ((iou > IOU_THR_C) && ((jbase + b) > i)) bits |= (1ull << b);
            }
        }
        unsigned long long tmask = (jbase + 64 <= nv) ? ~0ull
                                   : ((1ull << (nv - jbase)) - 1ull);
        unsigned long long ebits = bits & tmask;
        int ec = __popcll(ebits);
        int pre = ec;
#pragma unroll
        for (int d = 1; d < 64; d <<= 1) {
            int vv = __shfl_up(pre, d, 64);
            if (lane >= d) pre += vv;
        }
        int tot = __shfl(pre, 63, 64);
        if (tot > 0) {
            int ebase = 0;
            if (lane == 63) ebase = atomicAdd(ecntE, tot);
            ebase = __shfl(ebase, 63, 64);
            int idx = ebase + pre - ec;
            unsigned long long tb = ebits;
            while (tb) {
                int b = __builtin_ctzll(tb); tb &= tb - 1;
                if (idx < ecap)
                    edges[idx] = ((unsigned int)i << 13) | (unsigned int)(jbase + b);
                ++idx;
            }
        }
        __syncthreads();   // before next tile reuses cb
    }
    __syncthreads();
    if (t == 0) {
        __threadfence();                          // publish this block's edges
        isLastS = (atomicAdd(done2, 1) == PBLK - 1);
    }
    __syncthreads();
    if (!isLastS) return;
    __threadfence();                              // acquire all edges + count
    // --- Jacobi fixpoint (verified) ---
    int cnt = atomicAdd(ecntE, 0);
    if (t < NW) { unsigned long long v = validw[t]; sm.j.vL[t] = v; sm.j.kL[t] = v; }
    if (t == 0) { sm.j.chg[0] = 0; sm.j.chg[1] = 0; sm.j.chg[2] = 0; }
    if (cnt <= ecap) {
        int lim = cnt < LCAP ? cnt : LCAP;
        for (int e = t; e < lim; e += 1024) sm.j.eL[e] = edges[e];
    }
    __syncthreads();
    if (cnt <= ecap) {
        for (int it = 0; it < N_BOX; ++it) {
            if (t < NW) sm.j.tL[t] = 0ull;
            __syncthreads();
            for (int e = t; e < cnt; e += 1024) {
                unsigned int ed = (e < LCAP) ? sm.j.eL[e] : edges[e];
                int src = (int)(ed >> 13);
                if ((sm.j.kL[src >> 6] >> (src & 63)) & 1ull) {
                    int tg = (int)(ed & 8191u);
                    atomicOr(&sm.j.tL[tg >> 6], 1ull << (tg & 63));
                }
            }
            __syncthreads();
            if (t < NW) {
                unsigned long long nk = sm.j.vL[t] & ~sm.j.tL[t];
                if (nk != sm.j.kL[t]) sm.j.chg[it % 3] = 1;
                sm.j.kL[t] = nk;
            }
            if (t == 0) sm.j.chg[(it + 2) % 3] = 0;  // reset 2 barriers early
            __syncthreads();
            if (sm.j.chg[it % 3] == 0) break;        // uniform after barrier
        }
    } else {
        // fallback: serial greedy, IoU recomputed on the fly (one wave)
        if (t < NW) sm.j.tL[t] = ~sm.j.vL[t];
        __syncthreads();
        if (t < 64) {
            for (int i = 0; i < N_BOX - 1; ++i) {
                bool kept = !((sm.j.tL[i >> 6] >> (i & 63)) & 1ull);
                if (kept) {
                    float4 r = sb[i];
                    float ra = (r.z - r.x) * (r.w - r.y);
                    for (int jj = i + 1 + lane; jj < N_BOX; jj += 64) {
                        float4 c = sb[jj];
                        float ca = (c.z - c.x) * (c.w - c.y);
                        float iw = fminf(r.z, c.z) - fmaxf(r.x, c.x);
                        float ih = fminf(r.w, c.w) - fmaxf(r.y, c.y);
                        iw = fmaxf(iw, 0.0f);
                        ih = fmaxf(ih, 0.0f);
                        float inter = iw * ih;
                        float iou = inter / (ra + ca - inter + EPS_C);
                        if (iou > IOU_THR_C)
                            atomicOr(&sm.j.tL[jj >> 6], 1ull << (jj & 63));
                    }
                }
            }
        }
        __syncthreads();
        if (t < NW) sm.j.kL[t] = sm.j.vL[t] & ~sm.j.tL[t];
    }
    __syncthreads();
    // --- fused output: [boxes*SCALER*kf, conf*kf] (kL bit = KEEP) ---
    for (int i = t; i < N_BOX; i += 1024) {
        float kf = ((sm.j.kL[i >> 6] >> (i & 63)) & 1ull) ? 1.0f : 0.0f;
        float4 b = sb[i];
        unsigned int o = order[i];
        float s = kScaler * kf;
        out[i * 6 + 0] = b.x * s;
        out[i * 6 + 1] = b.y * s;
        out[i * 6 + 2] = b.z * s;
        out[i * 6 + 3] = b.w * s;
        out[i * 6 + 4] = conf[2 * o] * kf;
        out[i * 6 + 5] = conf[2 * o + 1] * kf;
    }
}

extern "C" void kernel_launch(void* const* d_in, const int* in_sizes, int n_in,
                              void* d_out, int out_size, void* d_ws, size_t ws_size,
                              hipStream_t stream) {
    const float* cls_conf = (const float*)d_in[0];   // (8192, 2)
    const float* bboxes   = (const float*)d_in[1];   // (8192, 4)
    float* out = (float*)d_out;                      // (8192, 6)

    char* ws = (char*)d_ws;
    unsigned long long* keys   = (unsigned long long*)(ws + 0);        //  64 KiB
    float4*             sb     = (float4*)(ws + 65536);                // 128 KiB
    unsigned int*       order  = (unsigned int*)(ws + 196608);         //  32 KiB
    unsigned long long* validw = (unsigned long long*)(ws + 229376);   //   1 KiB
    int*                ctrs   = (int*)(ws + 230400);                  //  16 B
    int*                ecntE  = ctrs + 0;
    int*                nvD    = ctrs + 1;
    int*                done1  = ctrs + 2;
    int*                done2  = ctrs + 3;
    const size_t EDGE_OFF = 237568;
    unsigned int*       edges  = (unsigned int*)(ws + EDGE_OFF);
    size_t avail = (ws_size > EDGE_OFF + 16) ? (ws_size - EDGE_OFF) / 4 : 0;
    int ecap = (int)(avail > (size_t)ECAP_MAX ? (size_t)ECAP_MAX : avail);

    hipMemsetAsync(ctrs, 0, 16, stream);   // zero ecntE / nvD / done1 / done2
    sort_kernel<<<4, 1024, 0, stream>>>(cls_conf, bboxes, keys, sb, order,
                                        validw, nvD, done1);
    pair_scan_kernel<<<PBLK, 1024, 0, stream>>>(sb, order, cls_conf, validw,
                                                nvD, edges, ecntE, done2,
                                                out, ecap);
}

// Round 14
// 143.862 us; speedup vs baseline: 1.2745x; 1.2745x over previous
//
#include <hip/hip_runtime.h>
#include <math.h>

#define N_BOX 8192
#define NW 128              // 8192 / 64 words
#define LCAP 24576          // edges staged in LDS for Jacobi (96 KiB)
#define SCAP 4096           // per-block staged edges in pair kernel (16 KiB)
#define ECAP_MAX (1 << 21)  // max edges in global buffer (8 MiB)
#define THR_C 0.7f
#define IOU_THR_C 0.5f
#define EPS_C 1e-9f

// SCALER = max(3508/1280, 2480/1280) computed in double then rounded to f32,
// matching numpy/jax float32 weak-typed scalar promotion.
__device__ __constant__ float kScaler = (float)(3508.0 / 1280.0);

static __device__ __forceinline__ unsigned long long make_key(const float* conf, int i) {
    float c0 = conf[2 * i], c1 = conf[2 * i + 1];
    bool valid = (c0 > THR_C) || (c1 > THR_C);
    float ms = valid ? fmaxf(c0, c1) : -INFINITY;
    unsigned int u = __float_as_uint(ms);
    unsigned int m = (u & 0x80000000u) ? ~u : (u | 0x80000000u); // ascending map
    unsigned int d = ~m;                                          // descending key
    return ((unsigned long long)d << 32) | (unsigned int)i;
}

// ---------------------------------------------------------------------------
// Sort stage 1: 4 blocks x 2048 elements, all k<=2048 passes LDS-local.
// Directions use GLOBAL indices -> network identical to the verified
// single-block bitonic sort. Block 0 also zero-inits the global counters.
// ---------------------------------------------------------------------------
__global__ __launch_bounds__(1024) void sort_local1(const float* __restrict__ conf,
                                                    unsigned long long* __restrict__ keys,
                                                    int* __restrict__ ecntE,
                                                    int* __restrict__ nvD) {
    __shared__ unsigned long long s[2048];
    int base = blockIdx.x * 2048;
    if (blockIdx.x == 0 && threadIdx.x == 0) { *ecntE = 0; *nvD = 0; }
    for (int l = threadIdx.x; l < 2048; l += 1024) s[l] = make_key(conf, base + l);
    __syncthreads();
    for (int k = 2; k <= 2048; k <<= 1) {
        for (int j = k >> 1; j > 0; j >>= 1) {
            int t = threadIdx.x;
            int i = ((t & ~(j - 1)) << 1) | (t & (j - 1));
            int p = i | j;
            bool up = (((base + i) & k) == 0);
            unsigned long long a = s[i], b = s[p];
            bool sw = up ? (a > b) : (a < b);
            if (sw) { s[i] = b; s[p] = a; }
            __syncthreads();
        }
    }
    for (int l = threadIdx.x; l < 2048; l += 1024) keys[base + l] = s[l];
}

// ---------------------------------------------------------------------------
// Sort stage 2 (fused k=4096 + k=8192) + gather. Each of 2 blocks loads ALL
// 8192 keys, runs the k=4096 merge phases on the full array in LDS, then the
// k=8192 j=4096 cross exchange for its own half, then j=2048..1 locally (all
// ascending), then consumes the sorted half directly from LDS: writes
// sb/order/validw and accumulates nv (valid boxes occupy ranks [0, nv)).
// ---------------------------------------------------------------------------
__global__ __launch_bounds__(1024) void sort_final2(const unsigned long long* __restrict__ keys,
                                                    const float* __restrict__ bboxes,
                                                    const float* __restrict__ conf,
                                                    float4* __restrict__ sb,
                                                    unsigned int* __restrict__ order,
                                                    unsigned long long* __restrict__ validw,
                                                    int* __restrict__ nvD) {
    __shared__ unsigned long long s[8192];   // 64 KiB
    int half = blockIdx.x;                   // 0 or 1
    int base = half << 12;
    int t = threadIdx.x;
    for (int l = t; l < 8192; l += 1024) s[l] = keys[l];
    __syncthreads();
    // k=4096 merge on the full array
    for (int j = 2048; j > 0; j >>= 1) {
        for (int t2 = t; t2 < 4096; t2 += 1024) {
            int i = ((t2 & ~(j - 1)) << 1) | (t2 & (j - 1));
            int p = i | j;
            bool up = ((i & 4096) == 0);
            unsigned long long a = s[i], b = s[p];
            bool sw = up ? (a > b) : (a < b);
            if (sw) { s[i] = b; s[p] = a; }
        }
        __syncthreads();
    }
    // k=8192, j=4096: min -> low half, max -> high half (all ascending)
    unsigned long long v4[4];
#pragma unroll
    for (int q = 0; q < 4; ++q) {
        int l = t + (q << 10);
        unsigned long long a = s[l], b = s[l + 4096];
        v4[q] = half ? (a > b ? a : b) : (a > b ? b : a);
    }
    __syncthreads();
#pragma unroll
    for (int q = 0; q < 4; ++q) s[base + t + (q << 10)] = v4[q];
    __syncthreads();
    // j=2048..1 on own half (all ascending at k=8192)
    for (int j = 2048; j > 0; j >>= 1) {
        for (int t2 = t; t2 < 2048; t2 += 1024) {
            int i = base + (((t2 & ~(j - 1)) << 1) | (t2 & (j - 1)));
            int p = i | j;
            unsigned long long a = s[i], b = s[p];
            if (a > b) { s[i] = b; s[p] = a; }
        }
        __syncthreads();
    }
    for (int l = t; l < 4096; l += 1024) {
        int gi = base + l;
        unsigned int o = (unsigned int)(s[gi] & 0xffffffffull);
        order[gi] = o;
        sb[gi] = ((const float4*)bboxes)[o];
        float c0 = conf[2 * o], c1 = conf[2 * o + 1];
        unsigned long long vb = __ballot((c0 > THR_C) || (c1 > THR_C));
        if ((gi & 63) == 0) {
            validw[gi >> 6] = vb;
            atomicAdd(nvD, __popcll(vb));
        }
    }
}

// ---------------------------------------------------------------------------
// Kernel 3: pair kernel — compact edge list over the nv x nv upper triangle
// (valid boxes are exactly ranks [0,nv): invalid sort last with -inf keys).
// Edge = (src<<13)|tgt, both valid, iou > thr, tgt > src; exact IEEE fp32
// arithmetic identical to the reference.
// BLOCK-AGGREGATED append: waves prefix into an LDS counter + stage buffer,
// ONE global atomicAdd per block, coalesced LDS->global copy (edge order is
// irrelevant to the Jacobi fixpoint). Overflow past SCAP (never expected:
// <=16K possible, ~100 typical per block) appends directly.
// ---------------------------------------------------------------------------
__global__ void pair_kernel(const float4* __restrict__ sb,
                            const int* __restrict__ nvD,
                            unsigned int* __restrict__ edges,
                            int* __restrict__ ecntE,
                            int ecap) {
    __shared__ float4 cb[64];
    __shared__ float carea[64];
    __shared__ unsigned int stage[SCAP];
    __shared__ int blkCnt, gBase;
    int w = blockIdx.y;
    int jbase = w << 6;
    int ibase = blockIdx.x * 256;
    int nv = *nvD;
    if (ibase >= nv || jbase >= nv || jbase + 63 <= ibase) return;  // uniform
    if (threadIdx.x == 0) blkCnt = 0;
    if (threadIdx.x < 64) {
        float4 c = sb[jbase + threadIdx.x];
        cb[threadIdx.x] = c;
        carea[threadIdx.x] = (c.z - c.x) * (c.w - c.y);
    }
    __syncthreads();
    int i = ibase + threadIdx.x;
    unsigned long long bits = 0ull;
    if (i < nv && jbase + 63 > i) {
        float4 r = sb[i];
        float ra = (r.z - r.x) * (r.w - r.y);
#pragma unroll 8
        for (int b = 0; b < 64; ++b) {
            float4 c = cb[b];
            float iw = fminf(r.z, c.z) - fmaxf(r.x, c.x);
            float ih = fminf(r.w, c.w) - fmaxf(r.y, c.y);
            iw = fmaxf(iw, 0.0f);
            ih = fmaxf(ih, 0.0f);
            float inter = iw * ih;
            float iou = inter / (ra + carea[b] - inter + EPS_C);
            if ((iou > IOU_THR_C) && ((jbase + b) > i)) bits |= (1ull << b);
        }
    }
    // drop targets >= nv (invalid: can never be kept)
    unsigned long long tmask = (jbase + 64 <= nv) ? ~0ull
                               : ((1ull << (nv - jbase)) - 1ull);
    unsigned long long ebits = bits & tmask;
    int lane = threadIdx.x & 63;
    int ec = __popcll(ebits);
    int pre = ec;
#pragma unroll
    for (int d = 1; d < 64; d <<= 1) {
        int vv = __shfl_up(pre, d, 64);
        if (lane >= d) pre += vv;
    }
    int tot = __shfl(pre, 63, 64);
    int wvBase = 0;
    if (lane == 63 && tot > 0) wvBase = atomicAdd(&blkCnt, tot);  // LDS atomic
    wvBase = __shfl(wvBase, 63, 64);
    int idx = wvBase + pre - ec;
    unsigned long long tb = ebits;
    while (tb) {
        int b = __builtin_ctzll(tb); tb &= tb - 1;
        unsigned int ed = ((unsigned int)i << 13) | (unsigned int)(jbase + b);
        if (idx < SCAP) stage[idx] = ed;
        else { int gi = atomicAdd(ecntE, 1); if (gi < ecap) edges[gi] = ed; }
        ++idx;
    }
    __syncthreads();
    int cnt = blkCnt < SCAP ? blkCnt : SCAP;
    if (threadIdx.x == 0 && cnt > 0) gBase = atomicAdd(ecntE, cnt); // ONE per block
    __syncthreads();
    for (int e = threadIdx.x; e < cnt; e += 256) {
        int gi = gBase + e;
        if (gi < ecap) edges[gi] = stage[e];
    }
}

// ---------------------------------------------------------------------------
// Kernel 4: Jacobi-iterated greedy NMS over the edge list (256 threads,
// 4-wave barriers) + FUSED OUTPUT. Greedy NMS is the unique fixpoint of
// k[i] = v[i] & ~OR_{j<i,e(j,i)} k[j]; Jacobi sweeps are exact for nodes of
// dependency depth <= t-1, so k_new == k_old certifies convergence. Keep bits
// never leave LDS. Overflow (cnt > ecap, never expected) falls back to an
// on-the-fly serial greedy recomputing IoU from sb — slow but correct.
// ---------------------------------------------------------------------------
__global__ __launch_bounds__(256) void scan_out_kernel(const unsigned int* __restrict__ edges,
                                                       const int* __restrict__ ecntE,
                                                       const unsigned long long* __restrict__ validw,
                                                       const float4* __restrict__ sb,
                                                       const unsigned int* __restrict__ order,
                                                       const float* __restrict__ conf,
                                                       float* __restrict__ out,
                                                       int ecap) {
    __shared__ unsigned int eL[LCAP];             // 96 KiB
    __shared__ unsigned long long kL[NW], tL[NW], vL[NW];
    __shared__ int chg[3];
    int t = threadIdx.x;
    int cnt = *ecntE;
    if (t < NW) { unsigned long long v = validw[t]; vL[t] = v; kL[t] = v; }
    if (t == 0) { chg[0] = 0; chg[1] = 0; chg[2] = 0; }
    if (cnt <= ecap) {
        int lim = cnt < LCAP ? cnt : LCAP;
        for (int e = t; e < lim; e += 256) eL[e] = edges[e];
    }
    __syncthreads();
    if (cnt <= ecap) {
        for (int it = 0; it < N_BOX; ++it) {
            if (t < NW) tL[t] = 0ull;
            __syncthreads();
            for (int e = t; e < cnt; e += 256) {
                unsigned int ed = (e < LCAP) ? eL[e] : edges[e];
                int src = (int)(ed >> 13);
                if ((kL[src >> 6] >> (src & 63)) & 1ull) {
                    int tg = (int)(ed & 8191u);
                    atomicOr(&tL[tg >> 6], 1ull << (tg & 63));
                }
            }
            __syncthreads();
            if (t < NW) {
                unsigned long long nk = vL[t] & ~tL[t];
                if (nk != kL[t]) chg[it % 3] = 1;
                kL[t] = nk;
            }
            if (t == 0) chg[(it + 2) % 3] = 0;   // reset 2 barriers before reuse
            __syncthreads();
            if (chg[it % 3] == 0) break;         // uniform: read after barrier
        }
    } else {
        // fallback: serial greedy, IoU recomputed on the fly (one wave)
        if (t < NW) tL[t] = ~vL[t];              // removed = !valid
        __syncthreads();
        if (t < 64) {
            int lane = t;
            for (int i = 0; i < N_BOX - 1; ++i) {
                bool kept = !((tL[i >> 6] >> (i & 63)) & 1ull);
                if (kept) {
                    float4 r = sb[i];
                    float ra = (r.z - r.x) * (r.w - r.y);
                    for (int j = i + 1 + lane; j < N_BOX; j += 64) {
                        float4 c = sb[j];
                        float ca = (c.z - c.x) * (c.w - c.y);
                        float iw = fminf(r.z, c.z) - fmaxf(r.x, c.x);
                        float ih = fminf(r.w, c.w) - fmaxf(r.y, c.y);
                        iw = fmaxf(iw, 0.0f);
                        ih = fmaxf(ih, 0.0f);
                        float inter = iw * ih;
                        float iou = inter / (ra + ca - inter + EPS_C);
                        if (iou > IOU_THR_C) atomicOr(&tL[j >> 6], 1ull << (j & 63));
                    }
                }
            }
        }
        __syncthreads();
        if (t < NW) kL[t] = vL[t] & ~tL[t];
    }
    __syncthreads();
    // fused output: [boxes*SCALER*kf, conf*kf]  (kL bit = KEEP)
    for (int i = t; i < N_BOX; i += 256) {
        float kf = ((kL[i >> 6] >> (i & 63)) & 1ull) ? 1.0f : 0.0f;
        float4 b = sb[i];
        unsigned int o = order[i];
        float s = kScaler * kf;
        out[i * 6 + 0] = b.x * s;
        out[i * 6 + 1] = b.y * s;
        out[i * 6 + 2] = b.z * s;
        out[i * 6 + 3] = b.w * s;
        out[i * 6 + 4] = conf[2 * o] * kf;
        out[i * 6 + 5] = conf[2 * o + 1] * kf;
    }
}

extern "C" void kernel_launch(void* const* d_in, const int* in_sizes, int n_in,
                              void* d_out, int out_size, void* d_ws, size_t ws_size,
                              hipStream_t stream) {
    const float* cls_conf = (const float*)d_in[0];   // (8192, 2)
    const float* bboxes   = (const float*)d_in[1];   // (8192, 4)
    float* out = (float*)d_out;                      // (8192, 6)

    char* ws = (char*)d_ws;
    unsigned long long* keys   = (unsigned long long*)(ws + 0);        //  64 KiB
    float4*             sb     = (float4*)(ws + 65536);                // 128 KiB
    unsigned int*       order  = (unsigned int*)(ws + 196608);         //  32 KiB
    unsigned long long* validw = (unsigned long long*)(ws + 229376);   //   1 KiB
    int*                ecntE  = (int*)(ws + 230400);                  //   4 B
    int*                nvD    = (int*)(ws + 230408);                  //   4 B
    const size_t EDGE_OFF = 237568;
    unsigned int*       edges  = (unsigned int*)(ws + EDGE_OFF);
    size_t avail = (ws_size > EDGE_OFF + 16) ? (ws_size - EDGE_OFF) / 4 : 0;
    int ecap = (int)(avail > (size_t)ECAP_MAX ? (size_t)ECAP_MAX : avail);

    sort_local1<<<4, 1024, 0, stream>>>(cls_conf, keys, ecntE, nvD);
    sort_final2<<<2, 1024, 0, stream>>>(keys, bboxes, cls_conf, sb, order, validw, nvD);
    pair_kernel<<<dim3(32, 128), 256, 0, stream>>>(sb, nvD, edges, ecntE, ecap);
    scan_out_kernel<<<1, 256, 0, stream>>>(edges, ecntE, validw, sb, order,
                                           cls_conf, out, ecap);
}